// Round 14
// baseline (83.746 us; speedup 1.0000x reference)
//
#include <hip/hip_runtime.h>

#define BATCH 4
#define NS    512
#define XS    1024

#define NT    4096
#define RMAX  96.0f
#define HSTEP (RMAX / (float)NT)
#define INVH  ((float)NT / RMAX)

#define C2    2.8853900817779268f   // 2*log2(e)
#define MAGIC 0x5EEDF00Du

typedef float f32x4 __attribute__((ext_vector_type(4)));

__device__ __forceinline__ float bcast(float v, int lane) {   // compile-time lane
    return __builtin_bit_cast(float, __builtin_amdgcn_readlane(__builtin_bit_cast(int, v), lane));
}

// One dispatch: 512 blocks x 512 threads (8 waves).
//   Phase A: wave wv of block bid builds table entry e = bid*8+wv (lane = feature).
//   Barrier: per-block MAGIC flag, device scope; all blocks co-resident (2/CU).
//   Phase B: wave wv integrates x-point xp = bid*8+wv (8 sensors per lane).
extern "C" __global__ __launch_bounds__(512)
void neurop_fused(const float* __restrict__ yu, const float* __restrict__ x,
                  const float* __restrict__ W_in, const float* __restrict__ b_in,
                  const float* __restrict__ W_h, const float* __restrict__ b_h,
                  const float* __restrict__ W_out, const float* __restrict__ b_out,
                  float* __restrict__ K, unsigned int* __restrict__ flags,
                  float* __restrict__ out)
{
    const int t   = threadIdx.x;
    const int l   = t & 63;          // lane: feature (A) / sensor-group (B)
    const int wv  = t >> 6;          // wave 0..7
    const int bid = blockIdx.x;

    // ---------------- Phase A: build K[bid*8+wv] ----------------
    {
        const int e  = bid * 8 + wv;
        const float r = (float)e * HSTEP;
        float h = fmaf(r, W_in[l], b_in[l]);

        #pragma unroll 1
        for (int d = 0; d < 6; ++d) {
            const float* __restrict__ W = W_h + (d << 12);   // W[i][j] row-major
            float hn = b_h[(d << 6) + l];
            #pragma unroll
            for (int i = 0; i < 64; ++i)
                hn = fmaf(bcast(h, i), W[(i << 6) + l], hn); // coalesced across lanes
            // h += tanh(hn):  tanh(z) = 1 - 2/(exp2(C2*z)+1)
            float ex = __builtin_amdgcn_exp2f(C2 * hn);
            float rc = __builtin_amdgcn_rcpf(ex + 1.0f);
            h = fmaf(-2.0f, rc, h + 1.0f);
        }

        float p = h * W_out[l];
        #pragma unroll
        for (int off = 1; off < 64; off <<= 1)
            p += __shfl_xor(p, off);
        if (l == 0) K[e] = p + b_out[0];
    }
    __syncthreads();                       // block's 8 entries written
    if (t == 0)
        __hip_atomic_store(&flags[bid], MAGIC, __ATOMIC_RELEASE, __HIP_MEMORY_SCOPE_AGENT);

    // ---------------- Device-wide barrier: wait for all 512 block flags ----------------
    // (thread t watches flag t; stale MAGIC from a previous replay is harmless:
    //  the table values it protects are bit-identical every call)
    while (__hip_atomic_load(&flags[t], __ATOMIC_ACQUIRE, __HIP_MEMORY_SCOPE_AGENT) != MAGIC)
        __builtin_amdgcn_s_sleep(8);
    __syncthreads();
    __builtin_amdgcn_fence(__ATOMIC_ACQUIRE, "agent");

    // ---------------- Phase B: integrate xp = bid*8+wv ----------------
    {
        const int xp = bid * 8 + wv;       // b*XS + xi
        const int b  = xp >> 10;
        const float x0 = x[xp * 2 + 0];
        const float x1 = x[xp * 2 + 1];

        float a0 = 0.0f, a1 = 0.0f, a2 = 0.0f;
        #pragma unroll
        for (int c = 0; c < 8; ++c) {
            const int s = c * 64 + l;
            const float* ur = yu + (b * NS + s) * 5;
            f32x4 uy;                      // u0,u1,u2,y0 (4B-aligned 16B load)
            __builtin_memcpy(&uy, ur, 16);
            const float y1v = ur[4];
            const float d0 = x0 - uy.w, d1 = x1 - y1v;
            const float r  = d0 * d0 + d1 * d1;

            float tt = fminf(r * INVH, (float)NT - 1.5f);   // i <= NT-2
            int   i  = (int)tt;
            float f  = tt - (float)i;
            float k0 = K[i], k1 = K[i + 1];
            float k  = fmaf(f, k1 - k0, k0);

            a0 = fmaf(k, uy.x, a0);
            a1 = fmaf(k, uy.y, a1);
            a2 = fmaf(k, uy.z, a2);
        }
        #pragma unroll
        for (int off = 1; off < 64; off <<= 1) {
            a0 += __shfl_xor(a0, off);
            a1 += __shfl_xor(a1, off);
            a2 += __shfl_xor(a2, off);
        }
        if (l == 0) {
            out[xp * 3 + 0] = a0 * (1.0f / (float)NS);
            out[xp * 3 + 1] = a1 * (1.0f / (float)NS);
            out[xp * 3 + 2] = a2 * (1.0f / (float)NS);
        }
    }
}

extern "C" void kernel_launch(void* const* d_in, const int* in_sizes, int n_in,
                              void* d_out, int out_size, void* d_ws, size_t ws_size,
                              hipStream_t stream) {
    const float* yu    = (const float*)d_in[0];
    const float* x     = (const float*)d_in[1];
    const float* W_in  = (const float*)d_in[2];
    const float* b_in  = (const float*)d_in[3];
    const float* W_h   = (const float*)d_in[4];
    const float* b_h   = (const float*)d_in[5];
    const float* W_out = (const float*)d_in[6];
    const float* b_out = (const float*)d_in[7];
    float* out = (float*)d_out;
    float*        K     = (float*)d_ws;                        // 4096*4 = 16 KB
    unsigned int* flags = (unsigned int*)((char*)d_ws + 16384); // 512*4

    hipLaunchKernelGGL(neurop_fused, dim3(512), dim3(512), 0, stream,
                       yu, x, W_in, b_in, W_h, b_h, W_out, b_out, K, flags, out);
}

// Round 15
// 21.149 us; speedup vs baseline: 3.9598x; 3.9598x over previous
//
#include <hip/hip_runtime.h>

#define BATCH 4
#define NS    512
#define XS    1024

#define NT    2048
#define RMAX  96.0f
#define HSTEP (RMAX / (float)NT)
#define INVH  ((float)NT / RMAX)

#define C2 2.8853900817779268f   // 2*log2(e)

typedef float f32x4 __attribute__((ext_vector_type(4)));

__device__ __forceinline__ float bcast(float v, int lane) {   // compile-time lane
    return __builtin_bit_cast(float, __builtin_amdgcn_readlane(__builtin_bit_cast(int, v), lane));
}

// ---- Kernel 1: tabulate k(r); one wave per TWO entries, one lane per feature.
//      Column loads W[(i<<6)+j]: lanes contiguous in j -> fully coalesced. ----
extern "C" __global__ __launch_bounds__(512)
void build_k_table(const float* __restrict__ W_in,
                   const float* __restrict__ b_in,
                   const float* __restrict__ W_h,
                   const float* __restrict__ b_h,
                   const float* __restrict__ W_out,
                   const float* __restrict__ b_out,
                   float* __restrict__ K)
{
    const int wv = threadIdx.x >> 6;            // wave in block
    const int j  = threadIdx.x & 63;            // feature owned by this lane
    const int e0 = (blockIdx.x * 8 + wv) * 2;   // first of two entries
    const float r0 = (float)e0 * HSTEP;
    const float r1 = (float)(e0 + 1) * HSTEP;

    const float wi = W_in[j], bi = b_in[j];
    float h0 = fmaf(r0, wi, bi);
    float h1 = fmaf(r1, wi, bi);

    #pragma unroll 1
    for (int d = 0; d < 6; ++d) {
        const float* __restrict__ W = W_h + (d << 12);   // W[i][j], row-major
        const float bb = b_h[(d << 6) + j];
        float hn0 = bb, hn1 = bb;
        #pragma unroll
        for (int i = 0; i < 64; ++i) {
            float w = W[(i << 6) + j];                   // coalesced across lanes
            hn0 = fmaf(bcast(h0, i), w, hn0);
            hn1 = fmaf(bcast(h1, i), w, hn1);
        }
        // h += tanh(hn):  tanh(z) = 1 - 2/(exp2(C2*z)+1)
        float ex0 = __builtin_amdgcn_exp2f(C2 * hn0);
        float ex1 = __builtin_amdgcn_exp2f(C2 * hn1);
        float rc0 = __builtin_amdgcn_rcpf(ex0 + 1.0f);
        float rc1 = __builtin_amdgcn_rcpf(ex1 + 1.0f);
        h0 = fmaf(-2.0f, rc0, h0 + 1.0f);
        h1 = fmaf(-2.0f, rc1, h1 + 1.0f);
    }

    const float wo = W_out[j];
    float p0 = h0 * wo, p1 = h1 * wo;
    #pragma unroll
    for (int off = 1; off < 64; off <<= 1) {
        p0 += __shfl_xor(p0, off);
        p1 += __shfl_xor(p1, off);
    }
    if (j == 0) {
        const float bo = b_out[0];
        K[e0]     = p0 + bo;
        K[e0 + 1] = p1 + bo;
    }
}

// ---- Kernel 2: one WAVE per x-point; 8 sensors per lane, local accumulate ----
extern "C" __global__ __launch_bounds__(256)
void integrate(const float* __restrict__ yu, const float* __restrict__ x,
               const float* __restrict__ K, float* __restrict__ out)
{
    const int t  = threadIdx.x;
    const int wv = t >> 6, l = t & 63;
    const int xp = blockIdx.x * 4 + wv;       // b*XS + xi
    const int b  = xp >> 10;

    const float x0 = x[xp * 2 + 0];
    const float x1 = x[xp * 2 + 1];

    float a0 = 0.0f, a1 = 0.0f, a2 = 0.0f;
    #pragma unroll
    for (int c = 0; c < 8; ++c) {
        const int s = c * 64 + l;
        const float* ur = yu + (b * NS + s) * 5;
        f32x4 uy;                              // u0,u1,u2,y0 (4B-aligned 16B load)
        __builtin_memcpy(&uy, ur, 16);
        const float y1v = ur[4];
        const float d0 = x0 - uy.w, d1 = x1 - y1v;
        const float r  = d0 * d0 + d1 * d1;

        float tt = fminf(r * INVH, (float)NT - 1.5f);   // i <= NT-2
        int   i  = (int)tt;
        float f  = tt - (float)i;
        float k0 = K[i], k1 = K[i + 1];
        float k  = fmaf(f, k1 - k0, k0);

        a0 = fmaf(k, uy.x, a0);
        a1 = fmaf(k, uy.y, a1);
        a2 = fmaf(k, uy.z, a2);
    }
    #pragma unroll
    for (int off = 1; off < 64; off <<= 1) {
        a0 += __shfl_xor(a0, off);
        a1 += __shfl_xor(a1, off);
        a2 += __shfl_xor(a2, off);
    }
    if (l == 0) {
        out[xp * 3 + 0] = a0 * (1.0f / (float)NS);
        out[xp * 3 + 1] = a1 * (1.0f / (float)NS);
        out[xp * 3 + 2] = a2 * (1.0f / (float)NS);
    }
}

extern "C" void kernel_launch(void* const* d_in, const int* in_sizes, int n_in,
                              void* d_out, int out_size, void* d_ws, size_t ws_size,
                              hipStream_t stream) {
    const float* yu    = (const float*)d_in[0];
    const float* x     = (const float*)d_in[1];
    const float* W_in  = (const float*)d_in[2];
    const float* b_in  = (const float*)d_in[3];
    const float* W_h   = (const float*)d_in[4];
    const float* b_h   = (const float*)d_in[5];
    const float* W_out = (const float*)d_in[6];
    const float* b_out = (const float*)d_in[7];
    float* out = (float*)d_out;
    float* K   = (float*)d_ws;    // NT * 4 = 8 KB

    hipLaunchKernelGGL(build_k_table, dim3(NT / 16), dim3(512), 0, stream,
                       W_in, b_in, W_h, b_h, W_out, b_out, K);
    hipLaunchKernelGGL(integrate, dim3(BATCH * XS / 4), dim3(256), 0, stream,
                       yu, x, (const float*)K, out);
}